// Round 3
// baseline (306.235 us; speedup 1.0000x reference)
//
#include <hip/hip_runtime.h>
#include <hip/hip_bf16.h>

// Problem constants
#define DD    256        // descriptor dim
#define KK    64         // clusters
#define NPIX  262144     // H*W
#define NW    512        // n-window per block (2 KB/row contiguous)
#define GRID  512        // NW * GRID == NPIX
#define BLOCK 1024       // 16 waves; 66.5 KB LDS + 64 VGPR -> 2 blocks/CU (32 waves)
#define NREP  16         // V-partial replicas

// LDS strides (elements)
#define AB_S  520        // abar: [64][520] bf16 (row 1040 B, 16B-mult)
#define XC_S  40         // phase-1 slice rows: 40 shorts = 80 B (16B-mult)
#define SV_S  129        // V stage: [64][129] f32 (half of d at a time)

typedef __attribute__((ext_vector_type(8))) short bf16x8;
typedef __attribute__((ext_vector_type(4))) float f32x4;

union Frag { bf16x8 v; int i[4]; };

__device__ __forceinline__ int cvtpk(float a, float b) {
    // packed f32->bf16 RNE; lowers to v_cvt_pk_bf16_f32 on gfx950
    __hip_bfloat162 h = __float22bfloat162_rn(float2{a, b});
    int r; __builtin_memcpy(&r, &h, 4); return r;  // low short = a
}

// lgkm-only barrier: LDS visibility without draining in-flight global loads
__device__ __forceinline__ void lds_barrier() {
    asm volatile("s_waitcnt lgkmcnt(0)" ::: "memory");
    __builtin_amdgcn_s_barrier();
}

__global__ __launch_bounds__(256)
void netvlad_wcvt(const float* __restrict__ conv_w, ushort* __restrict__ w8)
{
    int i = blockIdx.x * 256 + threadIdx.x;   // 64 blocks x 256 = 16384
    __hip_bfloat16 hb = __float2bfloat16(conv_w[i]);
    ushort s; __builtin_memcpy(&s, &hb, 2);
    w8[i] = s;
}

__global__ __launch_bounds__(BLOCK, 8)
void netvlad_fused(const float* __restrict__ x, const ushort* __restrict__ w8,
                   const float* __restrict__ conv_b, float* __restrict__ Vrep,
                   float* __restrict__ asum_rep)
{
    // Temporally-disjoint regions share one allocation:
    //   slice: phase-1 staging (dead after phase-1 MFMA loop)
    //   ab:    born after phase-1 (barrier-separated from slice)
    //   sv:    born in epilogue (barrier-separated from ab reads)
    __shared__ union {
        short ab[KK * AB_S];           // 66560 B
        short slice[16 * 32 * XC_S];   // 40960 B: 16 wave-private 32x40 xnd slices
        float sv[KK * SV_S];           // 33024 B: epilogue staging
    } U;
    // total 66560 B -> 2 blocks/CU

    const int t    = threadIdx.x;
    const int lane = t & 63;
    const int w    = t >> 6;        // wave 0..15
    const int l15  = lane & 15;
    const int q    = (lane >> 4) & 3;
    const int rep  = blockIdx.x & (NREP - 1);
    const size_t n0 = (size_t)blockIdx.x * NW;

    // ---- phase-1 load mapping: wave-private 32-col slice, chunks of 32 d ----
    const int dg = lane >> 3;            // 0..7  (4 d-rows each)
    const int ng = lane & 7;             // 0..7  (4 n-cols each)
    const size_t nself = n0 + 32 * w + 4 * ng;

    // prologue: chunks 0,1 in flight (depth-2)
    float4 pr[2][4];
    #pragma unroll
    for (int j = 0; j < 4; ++j)
        pr[0][j] = *(const float4*)(x + (size_t)(4 * dg + j) * NPIX + nself);
    __builtin_amdgcn_sched_barrier(0);   // pin: do not sink these loads
    #pragma unroll
    for (int j = 0; j < 4; ++j)
        pr[1][j] = *(const float4*)(x + (size_t)(32 + 4 * dg + j) * NPIX + nself);
    __builtin_amdgcn_sched_barrier(0);   // pin

    float breg[4][4];
    #pragma unroll
    for (int mt = 0; mt < 4; ++mt)
        #pragma unroll
        for (int r = 0; r < 4; ++r)
            breg[mt][r] = conv_b[16 * mt + 4 * q + r];

    // ================= PHASE 1: logits, wave-private, NO barriers =========
    // A-frags come straight from global bf16 W (32 KB, L1-resident).
    f32x4 Lc[2][4];
    #pragma unroll
    for (int nt = 0; nt < 2; ++nt)
        #pragma unroll
        for (int mt = 0; mt < 4; ++mt)
            Lc[nt][mt] = (f32x4){0.f, 0.f, 0.f, 0.f};

    short* slice = &U.slice[w * (32 * XC_S)];

    #pragma unroll
    for (int ch = 0; ch < 8; ++ch) {
        const int cur = ch & 1;

        // stage pr[cur] -> private slice (n-major micro-transpose), b64 writes
        {
            const float* r0 = (const float*)&pr[cur][0];
            const float* r1 = (const float*)&pr[cur][1];
            const float* r2 = (const float*)&pr[cur][2];
            const float* r3 = (const float*)&pr[cur][3];
            #pragma unroll
            for (int c = 0; c < 4; ++c) {
                int2 pk; pk.x = cvtpk(r0[c], r1[c]); pk.y = cvtpk(r2[c], r3[c]);
                *(int2*)&slice[(4 * ng + c) * XC_S + 4 * dg] = pk;
            }
        }

        // depth-2 prefetch: issue chunk ch+2 (regs just freed by staging)
        if (ch < 6) {
            #pragma unroll
            for (int j = 0; j < 4; ++j)
                pr[cur][j] = *(const float4*)(x + (size_t)(32 * (ch + 2) + 4 * dg + j) * NPIX + nself);
            __builtin_amdgcn_sched_barrier(0);   // pin: keep prefetch issued HERE
        }

        // frags + MFMA (contraction over this 32-d chunk)
        Frag Bv[2];
        #pragma unroll
        for (int nt = 0; nt < 2; ++nt)
            Bv[nt] = *(const Frag*)&slice[(16 * nt + l15) * XC_S + 8 * q];
        #pragma unroll
        for (int mt = 0; mt < 4; ++mt) {
            Frag A = *(const Frag*)&w8[(size_t)(16 * mt + l15) * DD + 32 * ch + 8 * q];
            #pragma unroll
            for (int nt = 0; nt < 2; ++nt)
                Lc[nt][mt] = __builtin_amdgcn_mfma_f32_16x16x32_bf16(A.v, Bv[nt].v, Lc[nt][mt], 0, 0, 0);
        }
    }

    lds_barrier();   // all waves done reading slices; U may be reused as ab

    // ---- softmax over k (in-register, wave-local) ----
    #pragma unroll
    for (int nt = 0; nt < 2; ++nt) {
        float mx = -1e30f;
        #pragma unroll
        for (int mt = 0; mt < 4; ++mt)
            #pragma unroll
            for (int r = 0; r < 4; ++r) {
                Lc[nt][mt][r] += breg[mt][r];
                mx = fmaxf(mx, Lc[nt][mt][r]);
            }
        mx = fmaxf(mx, __shfl_xor(mx, 16));
        mx = fmaxf(mx, __shfl_xor(mx, 32));
        float s = 0.f;
        #pragma unroll
        for (int mt = 0; mt < 4; ++mt)
            #pragma unroll
            for (int r = 0; r < 4; ++r) {
                float e = __expf(Lc[nt][mt][r] - mx);
                Lc[nt][mt][r] = e;
                s += e;
            }
        s += __shfl_xor(s, 16);
        s += __shfl_xor(s, 32);
        float inv = 1.0f / s;
        #pragma unroll
        for (int mt = 0; mt < 4; ++mt)
            #pragma unroll
            for (int r = 0; r < 4; ++r)
                Lc[nt][mt][r] *= inv;
    }

    // asum partials (sum over this wave's 32 cols)
    #pragma unroll
    for (int mt = 0; mt < 4; ++mt)
        #pragma unroll
        for (int r = 0; r < 4; ++r) {
            float v = Lc[0][mt][r] + Lc[1][mt][r];
            v += __shfl_xor(v, 1);
            v += __shfl_xor(v, 2);
            v += __shfl_xor(v, 4);
            v += __shfl_xor(v, 8);
            if (l15 == 0) atomicAdd(&asum_rep[rep * KK + 16 * mt + 4 * q + r], v);
        }

    // abar -> LDS (bf16), wave-private columns
    #pragma unroll
    for (int nt = 0; nt < 2; ++nt)
        #pragma unroll
        for (int mt = 0; mt < 4; ++mt)
            #pragma unroll
            for (int r = 0; r < 4; ++r) {
                __hip_bfloat16 hb = __float2bfloat16(Lc[nt][mt][r]);
                short s; __builtin_memcpy(&s, &hb, 2);
                U.ab[(16 * mt + 4 * q + r) * AB_S + 32 * w + 16 * nt + l15] = s;
            }

    // ---- phase-2 prologue: depth-4 pipeline issued BEFORE the barrier ----
    const float* xrow = x + (size_t)(16 * w + l15) * NPIX + n0 + 8 * q;
    float4 pv[4][2];
    #pragma unroll
    for (int d = 0; d < 4; ++d) {
        pv[d][0] = *(const float4*)(xrow + 32 * d);
        pv[d][1] = *(const float4*)(xrow + 32 * d + 4);
    }
    __builtin_amdgcn_sched_barrier(0);   // pin prologue issue

    lds_barrier();   // ALL abar visible; pv loads stay in flight

    // ========= PHASE 2: VLAD GEMM, direct-load A frags, NO barriers =======
    f32x4 acc[4];
    #pragma unroll
    for (int ct = 0; ct < 4; ++ct) acc[ct] = (f32x4){0.f, 0.f, 0.f, 0.f};

    #pragma unroll
    for (int s = 0; s < 16; ++s) {
        const int cur = s & 3;
        Frag Af;
        Af.i[0] = cvtpk(pv[cur][0].x, pv[cur][0].y);
        Af.i[1] = cvtpk(pv[cur][0].z, pv[cur][0].w);
        Af.i[2] = cvtpk(pv[cur][1].x, pv[cur][1].y);
        Af.i[3] = cvtpk(pv[cur][1].z, pv[cur][1].w);
        if (s < 12) {   // depth-4 prefetch
            pv[cur][0] = *(const float4*)(xrow + 32 * (s + 4));
            pv[cur][1] = *(const float4*)(xrow + 32 * (s + 4) + 4);
            __builtin_amdgcn_sched_barrier(0);   // pin: keep prefetch issued HERE
        }
        Frag Bf[4];
        #pragma unroll
        for (int ct = 0; ct < 4; ++ct)
            Bf[ct] = *(const Frag*)&U.ab[(16 * ct + l15) * AB_S + 32 * s + 8 * q];
        #pragma unroll
        for (int ct = 0; ct < 4; ++ct)
            acc[ct] = __builtin_amdgcn_mfma_f32_16x16x32_bf16(Af.v, Bf[ct].v, acc[ct], 0, 0, 0);
    }

    // ---- epilogue: V partial -> LDS (two d-halves) -> replica atomics ----
    // acc element (ct, r): k = 16ct + l15, d = 16w + 4q + r
    #pragma unroll
    for (int H = 0; H < 2; ++H) {
        __syncthreads();   // also fences ab reads (H=0) before sv overwrite
        if ((w >> 3) == H) {
            #pragma unroll
            for (int ct = 0; ct < 4; ++ct)
                #pragma unroll
                for (int r = 0; r < 4; ++r) {
                    int k  = 16 * ct + l15;
                    int dl = 16 * w + 4 * q + r - 128 * H;
                    U.sv[k * SV_S + dl] = acc[ct][r];
                }
        }
        __syncthreads();
        #pragma unroll
        for (int i = 0; i < 8; ++i) {
            int idx = t + BLOCK * i;       // 0..8191
            int k = idx >> 7, dl = idx & 127;
            atomicAdd(&Vrep[rep * (KK * DD) + k * DD + 128 * H + dl], U.sv[k * SV_S + dl]);
        }
    }
}

__global__ __launch_bounds__(256)
void netvlad_reduce(const float* __restrict__ Vrep, const float* __restrict__ asum_rep,
                    float* __restrict__ Vred, float* __restrict__ asum_red)
{
    int o = blockIdx.x * 256 + threadIdx.x;
    float s = 0.f;
    #pragma unroll
    for (int r = 0; r < NREP; ++r) s += Vrep[r * (KK * DD) + o];
    Vred[o] = s;
    if (blockIdx.x == 0 && threadIdx.x < KK) {
        float a = 0.f;
        #pragma unroll
        for (int r = 0; r < NREP; ++r) a += asum_rep[r * KK + threadIdx.x];
        asum_red[threadIdx.x] = a;
    }
}

__global__ __launch_bounds__(1024)
void netvlad_finalize(const float* __restrict__ Vws, const float* __restrict__ asum_ws,
                      const float* __restrict__ c, float* __restrict__ y)
{
    __shared__ float sV[KK * DD];
    __shared__ float sa[KK];
    __shared__ float colf[DD];
    __shared__ float rowf[KK];
    const int t = threadIdx.x;

    if (t < KK) sa[t] = asum_ws[t];
    __syncthreads();

    #pragma unroll
    for (int i = 0; i < 16; ++i) {
        int idx = t + 1024 * i;
        sV[idx] = Vws[idx] - c[idx] * sa[idx >> 8];
    }
    __syncthreads();

    if (t < DD) {   // column (d) norms over k
        float s = 0.f;
        for (int k = 0; k < KK; ++k) { float v = sV[k * DD + t]; s += v * v; }
        colf[t] = 1.0f / fmaxf(sqrtf(s), 1e-12f);
    }
    __syncthreads();

    #pragma unroll
    for (int i = 0; i < 16; ++i) {
        int idx = t + 1024 * i;
        sV[idx] *= colf[idx & 255];
    }
    __syncthreads();

    {   // row (k) norms over d: 16 threads per row
        int k = t >> 4, p = t & 15;
        float s = 0.f;
        #pragma unroll
        for (int j = 0; j < 16; ++j) { float v = sV[k * DD + p + 16 * j]; s += v * v; }
        s += __shfl_xor(s, 1);
        s += __shfl_xor(s, 2);
        s += __shfl_xor(s, 4);
        s += __shfl_xor(s, 8);
        if (p == 0) rowf[k] = 1.0f / fmaxf(sqrtf(s), 1e-12f);
    }
    __syncthreads();

    #pragma unroll
    for (int i = 0; i < 16; ++i) {
        int idx = t + 1024 * i;
        y[idx] = sV[idx] * rowf[idx >> 8];
    }
}

extern "C" void kernel_launch(void* const* d_in, const int* in_sizes, int n_in,
                              void* d_out, int out_size, void* d_ws, size_t ws_size,
                              hipStream_t stream) {
    const float* x      = (const float*)d_in[0];
    const float* c      = (const float*)d_in[1];
    const float* conv_w = (const float*)d_in[2];
    const float* conv_b = (const float*)d_in[3];
    float* y = (float*)d_out;

    float* Vrep     = (float*)d_ws;
    float* asum_rep = Vrep + NREP * KK * DD;
    float* Vred     = asum_rep + NREP * KK;
    float* asum_red = Vred + KK * DD;
    ushort* w8      = (ushort*)(asum_red + KK);   // 32 KB bf16 W, 16B-aligned

    hipMemsetAsync(d_ws, 0, (size_t)NREP * (KK * DD + KK) * sizeof(float), stream);
    netvlad_wcvt<<<64, 256, 0, stream>>>(conv_w, w8);
    netvlad_fused<<<GRID, BLOCK, 0, stream>>>(x, w8, conv_b, Vrep, asum_rep);
    netvlad_reduce<<<(KK * DD) / 256, 256, 0, stream>>>(Vrep, asum_rep, Vred, asum_red);
    netvlad_finalize<<<1, 1024, 0, stream>>>(Vred, asum_red, c, y);
}

// Round 4
// 187.131 us; speedup vs baseline: 1.6365x; 1.6365x over previous
//
#include <hip/hip_runtime.h>
#include <hip/hip_bf16.h>

// Problem constants
#define DD    256        // descriptor dim
#define KK    64         // clusters
#define NPIX  262144     // H*W
#define NW    256        // n-window per block
#define GRID  1024       // NW * GRID == NPIX
#define BLOCK 512        // 8 waves; 33.8 KB LDS, VGPR<=128 -> 2 blocks/CU (2 barrier domains)
#define NREP  16         // V-partial replicas

// LDS strides (elements)
#define AB_S  264        // abar: [64][264] bf16 (row 528 B, 16B-mult)
#define XC_S  40         // phase-1 slice rows: 40 shorts = 80 B (16B-mult)
#define SV_S  129        // V stage: [64][129] f32 (half of d at a time)

typedef __attribute__((ext_vector_type(8))) short bf16x8;
typedef __attribute__((ext_vector_type(4))) float f32x4;

union Frag { bf16x8 v; int i[4]; };

__device__ __forceinline__ int cvtpk(float a, float b) {
    // packed f32->bf16 RNE; lowers to v_cvt_pk_bf16_f32 on gfx950
    __hip_bfloat162 h = __float22bfloat162_rn(float2{a, b});
    int r; __builtin_memcpy(&r, &h, 4); return r;  // low short = a
}

// lgkm-only barrier: LDS visibility without draining in-flight global loads
__device__ __forceinline__ void lds_barrier() {
    asm volatile("s_waitcnt lgkmcnt(0)" ::: "memory");
    __builtin_amdgcn_s_barrier();
}

__global__ __launch_bounds__(256)
void netvlad_wcvt(const float* __restrict__ conv_w, ushort* __restrict__ w8)
{
    int i = blockIdx.x * 256 + threadIdx.x;   // 64 blocks x 256 = 16384
    __hip_bfloat16 hb = __float2bfloat16(conv_w[i]);
    ushort s; __builtin_memcpy(&s, &hb, 2);
    w8[i] = s;
}

__global__ __launch_bounds__(BLOCK, 4)   // waves_per_eu=4 -> VGPR cap 128 (8 is allocator poison: 32 regs + spills)
void netvlad_fused(const float* __restrict__ x, const ushort* __restrict__ w8,
                   const float* __restrict__ conv_b, float* __restrict__ Vrep,
                   float* __restrict__ asum_rep)
{
    // Temporally-disjoint regions share one allocation (barrier-separated):
    __shared__ union {
        short ab[KK * AB_S];           // 33792 B: abar for this block's 256 cols
        short slice[8 * 32 * XC_S];    // 20480 B: 8 wave-private 32x40 xnd slices
        float sv[KK * SV_S];           // 33024 B: epilogue staging
    } U;
    // total 33792 B -> LDS allows 4 blocks/CU; VGPR (~110) gives 2

    const int t    = threadIdx.x;
    const int lane = t & 63;
    const int w    = t >> 6;        // wave 0..7
    const int l15  = lane & 15;
    const int q    = (lane >> 4) & 3;
    const int rep  = blockIdx.x & (NREP - 1);
    const size_t n0 = (size_t)blockIdx.x * NW;

    // ---- phase-1 load mapping: wave-private 32-col slice, chunks of 32 d ----
    const int dg = lane >> 3;            // 0..7  (4 d-rows each)
    const int ng = lane & 7;             // 0..7  (4 n-cols each)
    const size_t nself = n0 + 32 * w + 4 * ng;

    // prologue: chunks 0,1 in flight (depth-2)
    float4 pr[2][4];
    #pragma unroll
    for (int j = 0; j < 4; ++j)
        pr[0][j] = *(const float4*)(x + (size_t)(4 * dg + j) * NPIX + nself);
    __builtin_amdgcn_sched_barrier(0);   // pin: do not sink these loads
    #pragma unroll
    for (int j = 0; j < 4; ++j)
        pr[1][j] = *(const float4*)(x + (size_t)(32 + 4 * dg + j) * NPIX + nself);
    __builtin_amdgcn_sched_barrier(0);   // pin

    float breg[4][4];
    #pragma unroll
    for (int mt = 0; mt < 4; ++mt)
        #pragma unroll
        for (int r = 0; r < 4; ++r)
            breg[mt][r] = conv_b[16 * mt + 4 * q + r];

    // ================= PHASE 1: logits, wave-private, NO barriers =========
    // A-frags straight from global bf16 W (32 KB, L1-resident).
    f32x4 Lc[2][4];
    #pragma unroll
    for (int nt = 0; nt < 2; ++nt)
        #pragma unroll
        for (int mt = 0; mt < 4; ++mt)
            Lc[nt][mt] = (f32x4){0.f, 0.f, 0.f, 0.f};

    short* slice = &U.slice[w * (32 * XC_S)];

    #pragma unroll
    for (int ch = 0; ch < 8; ++ch) {
        const int cur = ch & 1;

        // stage pr[cur] -> private slice (n-major micro-transpose), b64 writes
        {
            const float* r0 = (const float*)&pr[cur][0];
            const float* r1 = (const float*)&pr[cur][1];
            const float* r2 = (const float*)&pr[cur][2];
            const float* r3 = (const float*)&pr[cur][3];
            #pragma unroll
            for (int c = 0; c < 4; ++c) {
                int2 pk; pk.x = cvtpk(r0[c], r1[c]); pk.y = cvtpk(r2[c], r3[c]);
                *(int2*)&slice[(4 * ng + c) * XC_S + 4 * dg] = pk;
            }
        }

        // depth-2 prefetch: issue chunk ch+2 (regs just freed by staging)
        if (ch < 6) {
            #pragma unroll
            for (int j = 0; j < 4; ++j)
                pr[cur][j] = *(const float4*)(x + (size_t)(32 * (ch + 2) + 4 * dg + j) * NPIX + nself);
            __builtin_amdgcn_sched_barrier(0);   // pin: keep prefetch issued HERE
        }

        // frags + MFMA (contraction over this 32-d chunk)
        Frag Bv[2];
        #pragma unroll
        for (int nt = 0; nt < 2; ++nt)
            Bv[nt] = *(const Frag*)&slice[(16 * nt + l15) * XC_S + 8 * q];
        #pragma unroll
        for (int mt = 0; mt < 4; ++mt) {
            Frag A = *(const Frag*)&w8[(size_t)(16 * mt + l15) * DD + 32 * ch + 8 * q];
            #pragma unroll
            for (int nt = 0; nt < 2; ++nt)
                Lc[nt][mt] = __builtin_amdgcn_mfma_f32_16x16x32_bf16(A.v, Bv[nt].v, Lc[nt][mt], 0, 0, 0);
        }
    }

    lds_barrier();   // all waves done reading slices; U may be reused as ab

    // ---- softmax over k (in-register, wave-local) ----
    #pragma unroll
    for (int nt = 0; nt < 2; ++nt) {
        float mx = -1e30f;
        #pragma unroll
        for (int mt = 0; mt < 4; ++mt)
            #pragma unroll
            for (int r = 0; r < 4; ++r) {
                Lc[nt][mt][r] += breg[mt][r];
                mx = fmaxf(mx, Lc[nt][mt][r]);
            }
        mx = fmaxf(mx, __shfl_xor(mx, 16));
        mx = fmaxf(mx, __shfl_xor(mx, 32));
        float s = 0.f;
        #pragma unroll
        for (int mt = 0; mt < 4; ++mt)
            #pragma unroll
            for (int r = 0; r < 4; ++r) {
                float e = __expf(Lc[nt][mt][r] - mx);
                Lc[nt][mt][r] = e;
                s += e;
            }
        s += __shfl_xor(s, 16);
        s += __shfl_xor(s, 32);
        float inv = 1.0f / s;
        #pragma unroll
        for (int mt = 0; mt < 4; ++mt)
            #pragma unroll
            for (int r = 0; r < 4; ++r)
                Lc[nt][mt][r] *= inv;
    }

    // asum partials (sum over this wave's 32 cols)
    #pragma unroll
    for (int mt = 0; mt < 4; ++mt)
        #pragma unroll
        for (int r = 0; r < 4; ++r) {
            float v = Lc[0][mt][r] + Lc[1][mt][r];
            v += __shfl_xor(v, 1);
            v += __shfl_xor(v, 2);
            v += __shfl_xor(v, 4);
            v += __shfl_xor(v, 8);
            if (l15 == 0) atomicAdd(&asum_rep[rep * KK + 16 * mt + 4 * q + r], v);
        }

    // abar -> LDS (bf16), wave-private columns
    #pragma unroll
    for (int nt = 0; nt < 2; ++nt)
        #pragma unroll
        for (int mt = 0; mt < 4; ++mt)
            #pragma unroll
            for (int r = 0; r < 4; ++r) {
                __hip_bfloat16 hb = __float2bfloat16(Lc[nt][mt][r]);
                short s; __builtin_memcpy(&s, &hb, 2);
                U.ab[(16 * mt + 4 * q + r) * AB_S + 32 * w + 16 * nt + l15] = s;
            }

    // ---- phase-2 prologue: depth-2 pipeline issued BEFORE the barrier ----
    // wave w covers d-rows 32w+16*rg+l15, rg=0,1; float4 loads ARE the A-frag.
    const float* xrow0 = x + (size_t)(32 * w + l15) * NPIX + n0 + 8 * q;
    const float* xrow1 = x + (size_t)(32 * w + 16 + l15) * NPIX + n0 + 8 * q;
    float4 pv[2][2][2];   // [depth][rg][half]
    #pragma unroll
    for (int d = 0; d < 2; ++d) {
        pv[d][0][0] = *(const float4*)(xrow0 + 32 * d);
        pv[d][0][1] = *(const float4*)(xrow0 + 32 * d + 4);
        pv[d][1][0] = *(const float4*)(xrow1 + 32 * d);
        pv[d][1][1] = *(const float4*)(xrow1 + 32 * d + 4);
    }
    __builtin_amdgcn_sched_barrier(0);   // pin prologue issue

    lds_barrier();   // ALL abar visible; pv loads stay in flight

    // ========= PHASE 2: VLAD GEMM, direct-load A frags, NO barriers =======
    f32x4 acc[2][4];
    #pragma unroll
    for (int rg = 0; rg < 2; ++rg)
        #pragma unroll
        for (int ct = 0; ct < 4; ++ct) acc[rg][ct] = (f32x4){0.f, 0.f, 0.f, 0.f};

    #pragma unroll
    for (int s = 0; s < 8; ++s) {
        const int cur = s & 1;
        Frag Af[2];
        #pragma unroll
        for (int rg = 0; rg < 2; ++rg) {
            Af[rg].i[0] = cvtpk(pv[cur][rg][0].x, pv[cur][rg][0].y);
            Af[rg].i[1] = cvtpk(pv[cur][rg][0].z, pv[cur][rg][0].w);
            Af[rg].i[2] = cvtpk(pv[cur][rg][1].x, pv[cur][rg][1].y);
            Af[rg].i[3] = cvtpk(pv[cur][rg][1].z, pv[cur][rg][1].w);
        }
        if (s < 6) {   // depth-2 prefetch
            pv[cur][0][0] = *(const float4*)(xrow0 + 32 * (s + 2));
            pv[cur][0][1] = *(const float4*)(xrow0 + 32 * (s + 2) + 4);
            pv[cur][1][0] = *(const float4*)(xrow1 + 32 * (s + 2));
            pv[cur][1][1] = *(const float4*)(xrow1 + 32 * (s + 2) + 4);
            __builtin_amdgcn_sched_barrier(0);   // pin: keep prefetch issued HERE
        }
        Frag Bf[4];
        #pragma unroll
        for (int ct = 0; ct < 4; ++ct)
            Bf[ct] = *(const Frag*)&U.ab[(16 * ct + l15) * AB_S + 32 * s + 8 * q];
        #pragma unroll
        for (int ct = 0; ct < 4; ++ct) {
            acc[0][ct] = __builtin_amdgcn_mfma_f32_16x16x32_bf16(Af[0].v, Bf[ct].v, acc[0][ct], 0, 0, 0);
            acc[1][ct] = __builtin_amdgcn_mfma_f32_16x16x32_bf16(Af[1].v, Bf[ct].v, acc[1][ct], 0, 0, 0);
        }
    }

    // ---- epilogue: V partial -> LDS (two d-halves) -> replica atomics ----
    // acc element (rg, ct, r): k = 16ct + l15, d = 32w + 16rg + 4q + r
    #pragma unroll
    for (int H = 0; H < 2; ++H) {
        __syncthreads();   // fences ab reads (H=0) before sv overwrite
        #pragma unroll
        for (int rg = 0; rg < 2; ++rg) {
            const int dbase = 32 * w + 16 * rg;
            if ((dbase >> 7) == H) {
                #pragma unroll
                for (int ct = 0; ct < 4; ++ct)
                    #pragma unroll
                    for (int r = 0; r < 4; ++r) {
                        int k  = 16 * ct + l15;
                        int dl = dbase + 4 * q + r - 128 * H;
                        U.sv[k * SV_S + dl] = acc[rg][ct][r];
                    }
            }
        }
        __syncthreads();
        #pragma unroll
        for (int i = 0; i < 16; ++i) {
            int idx = t + BLOCK * i;       // 0..8191
            int k = idx >> 7, dl = idx & 127;
            atomicAdd(&Vrep[rep * (KK * DD) + k * DD + 128 * H + dl], U.sv[k * SV_S + dl]);
        }
    }
}

__global__ __launch_bounds__(256)
void netvlad_reduce(const float* __restrict__ Vrep, const float* __restrict__ asum_rep,
                    float* __restrict__ Vred, float* __restrict__ asum_red)
{
    int o = blockIdx.x * 256 + threadIdx.x;
    float s = 0.f;
    #pragma unroll
    for (int r = 0; r < NREP; ++r) s += Vrep[r * (KK * DD) + o];
    Vred[o] = s;
    if (blockIdx.x == 0 && threadIdx.x < KK) {
        float a = 0.f;
        #pragma unroll
        for (int r = 0; r < NREP; ++r) a += asum_rep[r * KK + threadIdx.x];
        asum_red[threadIdx.x] = a;
    }
}

__global__ __launch_bounds__(1024)
void netvlad_finalize(const float* __restrict__ Vws, const float* __restrict__ asum_ws,
                      const float* __restrict__ c, float* __restrict__ y)
{
    __shared__ float sV[KK * DD];
    __shared__ float sa[KK];
    __shared__ float colf[DD];
    __shared__ float rowf[KK];
    const int t = threadIdx.x;

    if (t < KK) sa[t] = asum_ws[t];
    __syncthreads();

    #pragma unroll
    for (int i = 0; i < 16; ++i) {
        int idx = t + 1024 * i;
        sV[idx] = Vws[idx] - c[idx] * sa[idx >> 8];
    }
    __syncthreads();

    if (t < DD) {   // column (d) norms over k
        float s = 0.f;
        for (int k = 0; k < KK; ++k) { float v = sV[k * DD + t]; s += v * v; }
        colf[t] = 1.0f / fmaxf(sqrtf(s), 1e-12f);
    }
    __syncthreads();

    #pragma unroll
    for (int i = 0; i < 16; ++i) {
        int idx = t + 1024 * i;
        sV[idx] *= colf[idx & 255];
    }
    __syncthreads();

    {   // row (k) norms over d: 16 threads per row
        int k = t >> 4, p = t & 15;
        float s = 0.f;
        #pragma unroll
        for (int j = 0; j < 16; ++j) { float v = sV[k * DD + p + 16 * j]; s += v * v; }
        s += __shfl_xor(s, 1);
        s += __shfl_xor(s, 2);
        s += __shfl_xor(s, 4);
        s += __shfl_xor(s, 8);
        if (p == 0) rowf[k] = 1.0f / fmaxf(sqrtf(s), 1e-12f);
    }
    __syncthreads();

    #pragma unroll
    for (int i = 0; i < 16; ++i) {
        int idx = t + 1024 * i;
        y[idx] = sV[idx] * rowf[idx >> 8];
    }
}

extern "C" void kernel_launch(void* const* d_in, const int* in_sizes, int n_in,
                              void* d_out, int out_size, void* d_ws, size_t ws_size,
                              hipStream_t stream) {
    const float* x      = (const float*)d_in[0];
    const float* c      = (const float*)d_in[1];
    const float* conv_w = (const float*)d_in[2];
    const float* conv_b = (const float*)d_in[3];
    float* y = (float*)d_out;

    float* Vrep     = (float*)d_ws;
    float* asum_rep = Vrep + NREP * KK * DD;
    float* Vred     = asum_rep + NREP * KK;
    float* asum_red = Vred + KK * DD;
    ushort* w8      = (ushort*)(asum_red + KK);   // 32 KB bf16 W, 16B-aligned

    hipMemsetAsync(d_ws, 0, (size_t)NREP * (KK * DD + KK) * sizeof(float), stream);
    netvlad_wcvt<<<64, 256, 0, stream>>>(conv_w, w8);
    netvlad_fused<<<GRID, BLOCK, 0, stream>>>(x, w8, conv_b, Vrep, asum_rep);
    netvlad_reduce<<<(KK * DD) / 256, 256, 0, stream>>>(Vrep, asum_rep, Vred, asum_red);
    netvlad_finalize<<<1, 1024, 0, stream>>>(Vred, asum_red, c, y);
}

// Round 5
// 176.600 us; speedup vs baseline: 1.7341x; 1.0596x over previous
//
#include <hip/hip_runtime.h>
#include <hip/hip_bf16.h>

// Problem constants
#define DD    256        // descriptor dim
#define KK    64         // clusters
#define NPIX  262144     // H*W
#define NW    512        // n-window per block (2 KB/row contiguous)
#define GRID  512        // NW * GRID == NPIX
#define BLOCK 1024       // 16 waves; 74.75 KB LDS + 64 VGPR -> 2 blocks/CU
#define NREP  16         // V-partial replicas

// LDS strides (elements)
#define W_S   264        // W:    [64][264] bf16 (row 528 B, 16B-mult)
#define AB_S  520        // abar: [64][520] bf16 (row 1040 B, 16B-mult)
#define XC_S  40         // phase-1 slice rows: 40 shorts = 80 B (16B-mult)
#define SV_S  129        // V stage: [64][129] f32 (half of d at a time)

typedef __attribute__((ext_vector_type(8))) short bf16x8;
typedef __attribute__((ext_vector_type(4))) float f32x4;

union Frag { bf16x8 v; int i[4]; };

__device__ __forceinline__ int cvtpk(float a, float b) {
    // packed f32->bf16 RNE; lowers to v_cvt_pk_bf16_f32 on gfx950
    __hip_bfloat162 h = __float22bfloat162_rn(float2{a, b});
    int r; __builtin_memcpy(&r, &h, 4); return r;  // low short = a
}

// lgkm-only barrier: LDS visibility without draining in-flight global loads
// (__syncthreads emits s_waitcnt vmcnt(0) which would kill cross-barrier prefetch)
__device__ __forceinline__ void lds_barrier() {
    asm volatile("s_waitcnt lgkmcnt(0)" ::: "memory");
    __builtin_amdgcn_s_barrier();
}

__global__ __launch_bounds__(BLOCK, 4)   // cap 128; code measured at 64 VGPR (R2). (.,8) is allocator poison.
void netvlad_fused(const float* __restrict__ x, const float* __restrict__ conv_w,
                   const float* __restrict__ conv_b, float* __restrict__ Vrep,
                   float* __restrict__ asum_rep)
{
    // Temporally-disjoint LDS regions share one 74752 B union:
    //   p1 (Wl + slices): live during phase 1 only
    //   ab:               born after phase-1 MFMA loop (lgkm barrier separates)
    //   sv:               born in epilogue (syncthreads separates from ab reads)
    // 2 x 74752 = 149.5 KB <= 160 KB -> 2 blocks/CU at VGPR<=64.
    __shared__ union {
        struct {
            short Wl[KK * W_S];           // 33792 B
            short slice[16 * 32 * XC_S];  // 40960 B: 16 wave-private 32x40 slices
        } p1;                             // 74752 B
        short ab[KK * AB_S];              // 66560 B
        float sv[KK * SV_S];              // 33024 B
    } U;

    const int t    = threadIdx.x;
    const int lane = t & 63;
    const int w    = t >> 6;        // wave 0..15
    const int l15  = lane & 15;
    const int q    = (lane >> 4) & 3;
    const int rep  = blockIdx.x & (NREP - 1);
    const size_t n0 = (size_t)blockIdx.x * NW;

    // ---- phase-1 load mapping: wave-private 32-col slice, chunks of 32 d ----
    const int dg = lane >> 3;            // 0..7  (4 d-rows each)
    const int ng = lane & 7;             // 0..7  (4 n-cols each)
    const size_t nself = n0 + 32 * w + 4 * ng;

    // prologue: chunk 0 loads (overlap W staging)
    float4 pr[2][4];
    #pragma unroll
    for (int j = 0; j < 4; ++j)
        pr[0][j] = *(const float4*)(x + (size_t)(4 * dg + j) * NPIX + nself);
    __builtin_amdgcn_sched_barrier(0);   // pin: do not sink these loads

    // ---- stage W (fp32 -> bf16) into LDS, once ----
    #pragma unroll
    for (int i = 0; i < 16; ++i) {
        int idx = t + BLOCK * i;                 // 0..16383
        float wv = conv_w[idx];
        __hip_bfloat16 hb = __float2bfloat16(wv);
        short s; __builtin_memcpy(&s, &hb, 2);
        U.p1.Wl[(idx >> 8) * W_S + (idx & 255)] = s;
    }

    // prologue: chunk 1 loads
    #pragma unroll
    for (int j = 0; j < 4; ++j)
        pr[1][j] = *(const float4*)(x + (size_t)(32 + 4 * dg + j) * NPIX + nself);
    __builtin_amdgcn_sched_barrier(0);   // pin

    float breg[4][4];
    #pragma unroll
    for (int mt = 0; mt < 4; ++mt)
        #pragma unroll
        for (int r = 0; r < 4; ++r)
            breg[mt][r] = conv_b[16 * mt + 4 * q + r];

    lds_barrier();   // W visible; pr loads stay in flight

    // ================= PHASE 1: logits, wave-private, NO barriers =========
    f32x4 Lc[2][4];
    #pragma unroll
    for (int nt = 0; nt < 2; ++nt)
        #pragma unroll
        for (int mt = 0; mt < 4; ++mt)
            Lc[nt][mt] = (f32x4){0.f, 0.f, 0.f, 0.f};

    short* slice = &U.p1.slice[w * (32 * XC_S)];

    #pragma unroll
    for (int ch = 0; ch < 8; ++ch) {
        const int cur = ch & 1;

        // stage pr[cur] -> private slice (n-major micro-transpose), b64 writes
        {
            const float* r0 = (const float*)&pr[cur][0];
            const float* r1 = (const float*)&pr[cur][1];
            const float* r2 = (const float*)&pr[cur][2];
            const float* r3 = (const float*)&pr[cur][3];
            #pragma unroll
            for (int c = 0; c < 4; ++c) {
                int2 pk; pk.x = cvtpk(r0[c], r1[c]); pk.y = cvtpk(r2[c], r3[c]);
                *(int2*)&slice[(4 * ng + c) * XC_S + 4 * dg] = pk;
            }
        }

        // depth-2 prefetch: issue chunk ch+2 (regs just freed by staging)
        if (ch < 6) {
            #pragma unroll
            for (int j = 0; j < 4; ++j)
                pr[cur][j] = *(const float4*)(x + (size_t)(32 * (ch + 2) + 4 * dg + j) * NPIX + nself);
            __builtin_amdgcn_sched_barrier(0);   // pin: keep prefetch issued HERE
        }

        // frags + MFMA (contraction over this 32-d chunk); A from LDS Wl
        // (A from global would FIFO-chain vmcnt behind the fresh prefetch -> vmcnt(0)/chunk)
        Frag Bv[2];
        #pragma unroll
        for (int nt = 0; nt < 2; ++nt)
            Bv[nt] = *(const Frag*)&slice[(16 * nt + l15) * XC_S + 8 * q];
        #pragma unroll
        for (int mt = 0; mt < 4; ++mt) {
            Frag A = *(const Frag*)&U.p1.Wl[(16 * mt + l15) * W_S + 32 * ch + 8 * q];
            #pragma unroll
            for (int nt = 0; nt < 2; ++nt)
                Lc[nt][mt] = __builtin_amdgcn_mfma_f32_16x16x32_bf16(A.v, Bv[nt].v, Lc[nt][mt], 0, 0, 0);
        }
    }

    lds_barrier();   // all waves done reading Wl+slices; U may be reused as ab

    // ---- softmax over k (in-register, wave-local) ----
    #pragma unroll
    for (int nt = 0; nt < 2; ++nt) {
        float mx = -1e30f;
        #pragma unroll
        for (int mt = 0; mt < 4; ++mt)
            #pragma unroll
            for (int r = 0; r < 4; ++r) {
                Lc[nt][mt][r] += breg[mt][r];
                mx = fmaxf(mx, Lc[nt][mt][r]);
            }
        mx = fmaxf(mx, __shfl_xor(mx, 16));
        mx = fmaxf(mx, __shfl_xor(mx, 32));
        float s = 0.f;
        #pragma unroll
        for (int mt = 0; mt < 4; ++mt)
            #pragma unroll
            for (int r = 0; r < 4; ++r) {
                float e = __expf(Lc[nt][mt][r] - mx);
                Lc[nt][mt][r] = e;
                s += e;
            }
        s += __shfl_xor(s, 16);
        s += __shfl_xor(s, 32);
        float inv = 1.0f / s;
        #pragma unroll
        for (int mt = 0; mt < 4; ++mt)
            #pragma unroll
            for (int r = 0; r < 4; ++r)
                Lc[nt][mt][r] *= inv;
    }

    // asum partials (sum over this wave's 32 cols)
    #pragma unroll
    for (int mt = 0; mt < 4; ++mt)
        #pragma unroll
        for (int r = 0; r < 4; ++r) {
            float v = Lc[0][mt][r] + Lc[1][mt][r];
            v += __shfl_xor(v, 1);
            v += __shfl_xor(v, 2);
            v += __shfl_xor(v, 4);
            v += __shfl_xor(v, 8);
            if (l15 == 0) atomicAdd(&asum_rep[rep * KK + 16 * mt + 4 * q + r], v);
        }

    // abar -> LDS (bf16), wave-private columns
    #pragma unroll
    for (int nt = 0; nt < 2; ++nt)
        #pragma unroll
        for (int mt = 0; mt < 4; ++mt)
            #pragma unroll
            for (int r = 0; r < 4; ++r) {
                __hip_bfloat16 hb = __float2bfloat16(Lc[nt][mt][r]);
                short s; __builtin_memcpy(&s, &hb, 2);
                U.ab[(16 * mt + 4 * q + r) * AB_S + 32 * w + 16 * nt + l15] = s;
            }

    // ---- phase-2 prologue: depth-4 pipeline issued BEFORE the barrier ----
    // lane l15 owns d-row 16w+l15; its float4 loads ARE the A-fragment.
    const float* xrow = x + (size_t)(16 * w + l15) * NPIX + n0 + 8 * q;
    float4 pv[4][2];
    #pragma unroll
    for (int d = 0; d < 4; ++d) {
        pv[d][0] = *(const float4*)(xrow + 32 * d);
        pv[d][1] = *(const float4*)(xrow + 32 * d + 4);
    }
    __builtin_amdgcn_sched_barrier(0);   // pin prologue issue

    lds_barrier();   // ALL abar visible; pv loads stay in flight

    // ========= PHASE 2: VLAD GEMM, direct-load A frags, NO barriers =======
    f32x4 acc[4];
    #pragma unroll
    for (int ct = 0; ct < 4; ++ct) acc[ct] = (f32x4){0.f, 0.f, 0.f, 0.f};

    #pragma unroll
    for (int s = 0; s < 16; ++s) {
        const int cur = s & 3;
        Frag Af;
        Af.i[0] = cvtpk(pv[cur][0].x, pv[cur][0].y);
        Af.i[1] = cvtpk(pv[cur][0].z, pv[cur][0].w);
        Af.i[2] = cvtpk(pv[cur][1].x, pv[cur][1].y);
        Af.i[3] = cvtpk(pv[cur][1].z, pv[cur][1].w);
        if (s < 12) {   // depth-4 prefetch
            pv[cur][0] = *(const float4*)(xrow + 32 * (s + 4));
            pv[cur][1] = *(const float4*)(xrow + 32 * (s + 4) + 4);
            __builtin_amdgcn_sched_barrier(0);   // pin: keep prefetch issued HERE
        }
        Frag Bf[4];
        #pragma unroll
        for (int ct = 0; ct < 4; ++ct)
            Bf[ct] = *(const Frag*)&U.ab[(16 * ct + l15) * AB_S + 32 * s + 8 * q];
        #pragma unroll
        for (int ct = 0; ct < 4; ++ct)
            acc[ct] = __builtin_amdgcn_mfma_f32_16x16x32_bf16(Af.v, Bf[ct].v, acc[ct], 0, 0, 0);
    }

    // ---- epilogue: V partial -> LDS (two d-halves) -> replica atomics ----
    // acc element (ct, r): k = 16ct + l15, d = 16w + 4q + r
    #pragma unroll
    for (int H = 0; H < 2; ++H) {
        __syncthreads();   // fences ab reads (H=0) before sv overwrite
        if ((w >> 3) == H) {
            #pragma unroll
            for (int ct = 0; ct < 4; ++ct)
                #pragma unroll
                for (int r = 0; r < 4; ++r) {
                    int k  = 16 * ct + l15;
                    int dl = 16 * w + 4 * q + r - 128 * H;
                    U.sv[k * SV_S + dl] = acc[ct][r];
                }
        }
        __syncthreads();
        #pragma unroll
        for (int i = 0; i < 8; ++i) {
            int idx = t + BLOCK * i;       // 0..8191
            int k = idx >> 7, dl = idx & 127;
            atomicAdd(&Vrep[rep * (KK * DD) + k * DD + 128 * H + dl], U.sv[k * SV_S + dl]);
        }
    }
}

__global__ __launch_bounds__(256)
void netvlad_reduce(const float* __restrict__ Vrep, const float* __restrict__ asum_rep,
                    float* __restrict__ Vred, float* __restrict__ asum_red)
{
    int o = blockIdx.x * 256 + threadIdx.x;
    float s = 0.f;
    #pragma unroll
    for (int r = 0; r < NREP; ++r) s += Vrep[r * (KK * DD) + o];
    Vred[o] = s;
    if (blockIdx.x == 0 && threadIdx.x < KK) {
        float a = 0.f;
        #pragma unroll
        for (int r = 0; r < NREP; ++r) a += asum_rep[r * KK + threadIdx.x];
        asum_red[threadIdx.x] = a;
    }
}

__global__ __launch_bounds__(1024)
void netvlad_finalize(const float* __restrict__ Vws, const float* __restrict__ asum_ws,
                      const float* __restrict__ c, float* __restrict__ y)
{
    __shared__ float sV[KK * DD];
    __shared__ float sa[KK];
    __shared__ float colf[DD];
    __shared__ float rowf[KK];
    const int t = threadIdx.x;

    if (t < KK) sa[t] = asum_ws[t];
    __syncthreads();

    #pragma unroll
    for (int i = 0; i < 16; ++i) {
        int idx = t + 1024 * i;
        sV[idx] = Vws[idx] - c[idx] * sa[idx >> 8];
    }
    __syncthreads();

    if (t < DD) {   // column (d) norms over k
        float s = 0.f;
        for (int k = 0; k < KK; ++k) { float v = sV[k * DD + t]; s += v * v; }
        colf[t] = 1.0f / fmaxf(sqrtf(s), 1e-12f);
    }
    __syncthreads();

    #pragma unroll
    for (int i = 0; i < 16; ++i) {
        int idx = t + 1024 * i;
        sV[idx] *= colf[idx & 255];
    }
    __syncthreads();

    {   // row (k) norms over d: 16 threads per row
        int k = t >> 4, p = t & 15;
        float s = 0.f;
        #pragma unroll
        for (int j = 0; j < 16; ++j) { float v = sV[k * DD + p + 16 * j]; s += v * v; }
        s += __shfl_xor(s, 1);
        s += __shfl_xor(s, 2);
        s += __shfl_xor(s, 4);
        s += __shfl_xor(s, 8);
        if (p == 0) rowf[k] = 1.0f / fmaxf(sqrtf(s), 1e-12f);
    }
    __syncthreads();

    #pragma unroll
    for (int i = 0; i < 16; ++i) {
        int idx = t + 1024 * i;
        y[idx] = sV[idx] * rowf[idx >> 8];
    }
}

extern "C" void kernel_launch(void* const* d_in, const int* in_sizes, int n_in,
                              void* d_out, int out_size, void* d_ws, size_t ws_size,
                              hipStream_t stream) {
    const float* x      = (const float*)d_in[0];
    const float* c      = (const float*)d_in[1];
    const float* conv_w = (const float*)d_in[2];
    const float* conv_b = (const float*)d_in[3];
    float* y = (float*)d_out;

    float* Vrep     = (float*)d_ws;
    float* asum_rep = Vrep + NREP * KK * DD;
    float* Vred     = asum_rep + NREP * KK;
    float* asum_red = Vred + KK * DD;

    hipMemsetAsync(d_ws, 0, (size_t)NREP * (KK * DD + KK) * sizeof(float), stream);
    netvlad_fused<<<GRID, BLOCK, 0, stream>>>(x, conv_w, conv_b, Vrep, asum_rep);
    netvlad_reduce<<<(KK * DD) / 256, 256, 0, stream>>>(Vrep, asum_rep, Vred, asum_red);
    netvlad_finalize<<<1, 1024, 0, stream>>>(Vred, asum_red, c, y);
}

// Round 6
// 113.039 us; speedup vs baseline: 2.7091x; 1.5623x over previous
//
#include <hip/hip_runtime.h>
#include <hip/hip_bf16.h>

// Problem constants
#define DD    256        // descriptor dim
#define KK    64         // clusters
#define NPIX  262144     // H*W
#define NW    512        // n-window per block (2 KB/row contiguous)
#define GRID  512        // NW * GRID == NPIX
#define BLOCK 1024       // 16 waves, 1 block/CU (LDS-bound)

// LDS strides (elements)
#define W_S   264        // W:    [64][264] bf16 (row 528 B, 16B-mult)
#define AB_S  520        // abar: [64][520] bf16 (row 1040 B, 16B-mult)
#define XC_S  40         // phase-1 slice rows: 40 shorts = 80 B (16B-mult)
#define SV_S  129        // V stage: [64][129] f32 (half of d at a time)

typedef __attribute__((ext_vector_type(8))) short bf16x8;
typedef __attribute__((ext_vector_type(4))) float f32x4;

union Frag { bf16x8 v; int i[4]; };

__device__ __forceinline__ int cvtpk(float a, float b) {
    // packed f32->bf16 RNE; lowers to v_cvt_pk_bf16_f32 on gfx950
    __hip_bfloat162 h = __float22bfloat162_rn(float2{a, b});
    int r; __builtin_memcpy(&r, &h, 4); return r;  // low short = a
}

// lgkm-only barrier: LDS visibility without draining in-flight global loads
// (__syncthreads emits s_waitcnt vmcnt(0) which would kill cross-barrier prefetch)
__device__ __forceinline__ void lds_barrier() {
    asm volatile("s_waitcnt lgkmcnt(0)" ::: "memory");
    __builtin_amdgcn_s_barrier();
}

__global__ __launch_bounds__(BLOCK, 4)
void netvlad_fused(const float* __restrict__ x, const float* __restrict__ conv_w,
                   const float* __restrict__ conv_b, float* __restrict__ Vpart,
                   float* __restrict__ asum_part)
{
    __shared__ short Wl[KK * W_S];    // 33792 B
    __shared__ short Ab[KK * AB_S];   // 66560 B
    __shared__ union {
        short slice[16 * 32 * XC_S];  // 40960 B: 16 wave-private 32x40 xnd slices
        float sv[KK * SV_S];          // 33024 B: epilogue staging
    } U2;
    // total 141312 B -> 1 block/CU

    const int t    = threadIdx.x;
    const int lane = t & 63;
    const int w    = t >> 6;        // wave 0..15
    const int l15  = lane & 15;
    const int q    = (lane >> 4) & 3;
    const int bid  = blockIdx.x;
    const size_t n0 = (size_t)bid * NW;

    // ---- phase-1 load mapping: wave-private 32-col slice, chunks of 32 d ----
    const int dg = lane >> 3;            // 0..7  (4 d-rows each)
    const int ng = lane & 7;             // 0..7  (4 n-cols each)
    const size_t nself = n0 + 32 * w + 4 * ng;

    // prologue: chunk 0 loads (overlap W staging)
    float4 pr[2][4];
    #pragma unroll
    for (int j = 0; j < 4; ++j)
        pr[0][j] = *(const float4*)(x + (size_t)(4 * dg + j) * NPIX + nself);
    __builtin_amdgcn_sched_barrier(0);   // pin: do not sink these loads

    // ---- stage W (fp32 -> bf16) into LDS, once ----
    #pragma unroll
    for (int i = 0; i < 16; ++i) {
        int idx = t + BLOCK * i;                 // 0..16383
        float wv = conv_w[idx];
        __hip_bfloat16 hb = __float2bfloat16(wv);
        short s; __builtin_memcpy(&s, &hb, 2);
        Wl[(idx >> 8) * W_S + (idx & 255)] = s;
    }

    // prologue: chunk 1 loads
    #pragma unroll
    for (int j = 0; j < 4; ++j)
        pr[1][j] = *(const float4*)(x + (size_t)(32 + 4 * dg + j) * NPIX + nself);
    __builtin_amdgcn_sched_barrier(0);   // pin

    float breg[4][4];
    #pragma unroll
    for (int mt = 0; mt < 4; ++mt)
        #pragma unroll
        for (int r = 0; r < 4; ++r)
            breg[mt][r] = conv_b[16 * mt + 4 * q + r];

    lds_barrier();   // W visible; pr loads stay in flight

    // ================= PHASE 1: logits, wave-private, NO barriers =========
    f32x4 Lc[2][4];
    #pragma unroll
    for (int nt = 0; nt < 2; ++nt)
        #pragma unroll
        for (int mt = 0; mt < 4; ++mt)
            Lc[nt][mt] = (f32x4){0.f, 0.f, 0.f, 0.f};

    short* slice = &U2.slice[w * (32 * XC_S)];

    #pragma unroll
    for (int ch = 0; ch < 8; ++ch) {
        const int cur = ch & 1;

        // stage pr[cur] -> private slice (n-major micro-transpose), b64 writes
        {
            const float* r0 = (const float*)&pr[cur][0];
            const float* r1 = (const float*)&pr[cur][1];
            const float* r2 = (const float*)&pr[cur][2];
            const float* r3 = (const float*)&pr[cur][3];
            #pragma unroll
            for (int c = 0; c < 4; ++c) {
                int2 pk; pk.x = cvtpk(r0[c], r1[c]); pk.y = cvtpk(r2[c], r3[c]);
                *(int2*)&slice[(4 * ng + c) * XC_S + 4 * dg] = pk;
            }
        }

        // depth-2 prefetch: issue chunk ch+2 (regs just freed by staging)
        if (ch < 6) {
            #pragma unroll
            for (int j = 0; j < 4; ++j)
                pr[cur][j] = *(const float4*)(x + (size_t)(32 * (ch + 2) + 4 * dg + j) * NPIX + nself);
            __builtin_amdgcn_sched_barrier(0);   // pin: keep prefetch issued HERE
        }

        // frags + MFMA (contraction over this 32-d chunk); A from LDS Wl
        Frag Bv[2];
        #pragma unroll
        for (int nt = 0; nt < 2; ++nt)
            Bv[nt] = *(const Frag*)&slice[(16 * nt + l15) * XC_S + 8 * q];
        #pragma unroll
        for (int mt = 0; mt < 4; ++mt) {
            Frag A = *(const Frag*)&Wl[(16 * mt + l15) * W_S + 32 * ch + 8 * q];
            #pragma unroll
            for (int nt = 0; nt < 2; ++nt)
                Lc[nt][mt] = __builtin_amdgcn_mfma_f32_16x16x32_bf16(A.v, Bv[nt].v, Lc[nt][mt], 0, 0, 0);
        }
    }

    // ---- softmax over k (in-register, wave-local) ----
    #pragma unroll
    for (int nt = 0; nt < 2; ++nt) {
        float mx = -1e30f;
        #pragma unroll
        for (int mt = 0; mt < 4; ++mt)
            #pragma unroll
            for (int r = 0; r < 4; ++r) {
                Lc[nt][mt][r] += breg[mt][r];
                mx = fmaxf(mx, Lc[nt][mt][r]);
            }
        mx = fmaxf(mx, __shfl_xor(mx, 16));
        mx = fmaxf(mx, __shfl_xor(mx, 32));
        float s = 0.f;
        #pragma unroll
        for (int mt = 0; mt < 4; ++mt)
            #pragma unroll
            for (int r = 0; r < 4; ++r) {
                float e = __expf(Lc[nt][mt][r] - mx);
                Lc[nt][mt][r] = e;
                s += e;
            }
        s += __shfl_xor(s, 16);
        s += __shfl_xor(s, 32);
        float inv = 1.0f / s;
        #pragma unroll
        for (int mt = 0; mt < 4; ++mt)
            #pragma unroll
            for (int r = 0; r < 4; ++r)
                Lc[nt][mt][r] *= inv;
    }

    // asum partials (sum over this wave's 32 cols) -> wave-private LDS buf
    // (reuses this wave's now-dead slice region; NO global atomics)
    {
        float* buf = (float*)(U2.slice + w * (32 * XC_S));   // 64 floats, wave-private
        #pragma unroll
        for (int mt = 0; mt < 4; ++mt)
            #pragma unroll
            for (int r = 0; r < 4; ++r) {
                float v = Lc[0][mt][r] + Lc[1][mt][r];
                v += __shfl_xor(v, 1);
                v += __shfl_xor(v, 2);
                v += __shfl_xor(v, 4);
                v += __shfl_xor(v, 8);
                if (l15 == 0) buf[16 * mt + 4 * q + r] = v;
            }
    }

    // abar -> LDS (bf16), wave-private columns
    #pragma unroll
    for (int nt = 0; nt < 2; ++nt)
        #pragma unroll
        for (int mt = 0; mt < 4; ++mt)
            #pragma unroll
            for (int r = 0; r < 4; ++r) {
                __hip_bfloat16 hb = __float2bfloat16(Lc[nt][mt][r]);
                short s; __builtin_memcpy(&s, &hb, 2);
                Ab[(16 * mt + 4 * q + r) * AB_S + 32 * w + 16 * nt + l15] = s;
            }

    // ---- phase-2 prologue: depth-4 pipeline issued BEFORE the barrier ----
    // lane l15 owns d-row 16w+l15; its float4 loads ARE the A-fragment.
    const float* xrow = x + (size_t)(16 * w + l15) * NPIX + n0 + 8 * q;
    float4 pv[4][2];
    #pragma unroll
    for (int d = 0; d < 4; ++d) {
        pv[d][0] = *(const float4*)(xrow + 32 * d);
        pv[d][1] = *(const float4*)(xrow + 32 * d + 4);
    }
    __builtin_amdgcn_sched_barrier(0);   // pin prologue issue

    lds_barrier();   // ALL abar + asum bufs visible; pv loads stay in flight

    // ---- block asum: 64 threads sum the 16 wave-bufs, one plain store ----
    if (t < KK) {
        float s = 0.f;
        #pragma unroll
        for (int ww = 0; ww < 16; ++ww)
            s += ((const float*)(U2.slice + ww * (32 * XC_S)))[t];
        asum_part[(size_t)bid * KK + t] = s;
    }

    // ========= PHASE 2: VLAD GEMM, direct-load A frags, NO barriers =======
    f32x4 acc[4];
    #pragma unroll
    for (int ct = 0; ct < 4; ++ct) acc[ct] = (f32x4){0.f, 0.f, 0.f, 0.f};

    #pragma unroll
    for (int s = 0; s < 16; ++s) {
        const int cur = s & 3;
        Frag Af;
        Af.i[0] = cvtpk(pv[cur][0].x, pv[cur][0].y);
        Af.i[1] = cvtpk(pv[cur][0].z, pv[cur][0].w);
        Af.i[2] = cvtpk(pv[cur][1].x, pv[cur][1].y);
        Af.i[3] = cvtpk(pv[cur][1].z, pv[cur][1].w);
        if (s < 12) {   // depth-4 prefetch
            pv[cur][0] = *(const float4*)(xrow + 32 * (s + 4));
            pv[cur][1] = *(const float4*)(xrow + 32 * (s + 4) + 4);
            __builtin_amdgcn_sched_barrier(0);   // pin: keep prefetch issued HERE
        }
        Frag Bf[4];
        #pragma unroll
        for (int ct = 0; ct < 4; ++ct)
            Bf[ct] = *(const Frag*)&Ab[(16 * ct + l15) * AB_S + 32 * s + 8 * q];
        #pragma unroll
        for (int ct = 0; ct < 4; ++ct)
            acc[ct] = __builtin_amdgcn_mfma_f32_16x16x32_bf16(Af.v, Bf[ct].v, acc[ct], 0, 0, 0);
    }

    // ---- epilogue: V partial -> LDS (two d-halves) -> PLAIN coalesced stores ----
    // acc element (ct, r): k = 16ct + l15, d = 16w + 4q + r
    float* vout = Vpart + (size_t)bid * (KK * DD);
    #pragma unroll
    for (int H = 0; H < 2; ++H) {
        __syncthreads();
        if ((w >> 3) == H) {
            #pragma unroll
            for (int ct = 0; ct < 4; ++ct)
                #pragma unroll
                for (int r = 0; r < 4; ++r) {
                    int k  = 16 * ct + l15;
                    int dl = 16 * w + 4 * q + r - 128 * H;
                    U2.sv[k * SV_S + dl] = acc[ct][r];
                }
        }
        __syncthreads();
        #pragma unroll
        for (int i = 0; i < 8; ++i) {
            int idx = t + BLOCK * i;       // 0..8191
            int k = idx >> 7, dl = idx & 127;
            vout[k * DD + 128 * H + dl] = U2.sv[k * SV_S + dl];
        }
    }
}

__global__ __launch_bounds__(256)
void netvlad_reduce(const float* __restrict__ Vpart, const float* __restrict__ asum_part,
                    float* __restrict__ Vred, float* __restrict__ asum_red)
{
    __shared__ float sbuf[256];
    const int t = threadIdx.x;
    if (blockIdx.x < 256) {
        // V: each block produces 64 outputs; 4 thread-groups of 64 split the 512 blocks
        const int o    = blockIdx.x * 64 + (t & 63);
        const int part = t >> 6;
        float s = 0.f;
        #pragma unroll 8
        for (int i = 0; i < 128; ++i)
            s += Vpart[(size_t)(part * 128 + i) * (KK * DD) + o];
        sbuf[t] = s;
        __syncthreads();
        if (t < 64) Vred[o] = sbuf[t] + sbuf[t + 64] + sbuf[t + 128] + sbuf[t + 192];
    } else {
        // asum: 512 rows of 64
        const int k    = t & 63;
        const int part = t >> 6;
        float s = 0.f;
        #pragma unroll 8
        for (int i = 0; i < 128; ++i)
            s += asum_part[(size_t)(part * 128 + i) * KK + k];
        sbuf[t] = s;
        __syncthreads();
        if (t < 64) asum_red[k] = sbuf[t] + sbuf[t + 64] + sbuf[t + 128] + sbuf[t + 192];
    }
}

__global__ __launch_bounds__(1024)
void netvlad_finalize(const float* __restrict__ Vws, const float* __restrict__ asum_ws,
                      const float* __restrict__ c, float* __restrict__ y)
{
    __shared__ float sV[KK * DD];
    __shared__ float sa[KK];
    __shared__ float colf[DD];
    __shared__ float rowf[KK];
    const int t = threadIdx.x;

    if (t < KK) sa[t] = asum_ws[t];
    __syncthreads();

    #pragma unroll
    for (int i = 0; i < 16; ++i) {
        int idx = t + 1024 * i;
        sV[idx] = Vws[idx] - c[idx] * sa[idx >> 8];
    }
    __syncthreads();

    if (t < DD) {   // column (d) norms over k
        float s = 0.f;
        for (int k = 0; k < KK; ++k) { float v = sV[k * DD + t]; s += v * v; }
        colf[t] = 1.0f / fmaxf(sqrtf(s), 1e-12f);
    }
    __syncthreads();

    #pragma unroll
    for (int i = 0; i < 16; ++i) {
        int idx = t + 1024 * i;
        sV[idx] *= colf[idx & 255];
    }
    __syncthreads();

    {   // row (k) norms over d: 16 threads per row
        int k = t >> 4, p = t & 15;
        float s = 0.f;
        #pragma unroll
        for (int j = 0; j < 16; ++j) { float v = sV[k * DD + p + 16 * j]; s += v * v; }
        s += __shfl_xor(s, 1);
        s += __shfl_xor(s, 2);
        s += __shfl_xor(s, 4);
        s += __shfl_xor(s, 8);
        if (p == 0) rowf[k] = 1.0f / fmaxf(sqrtf(s), 1e-12f);
    }
    __syncthreads();

    #pragma unroll
    for (int i = 0; i < 16; ++i) {
        int idx = t + 1024 * i;
        y[idx] = sV[idx] * rowf[idx >> 8];
    }
}

extern "C" void kernel_launch(void* const* d_in, const int* in_sizes, int n_in,
                              void* d_out, int out_size, void* d_ws, size_t ws_size,
                              hipStream_t stream) {
    const float* x      = (const float*)d_in[0];
    const float* c      = (const float*)d_in[1];
    const float* conv_w = (const float*)d_in[2];
    const float* conv_b = (const float*)d_in[3];
    float* y = (float*)d_out;

    // workspace: 512*16384 + 512*64 + 16384 + 64 floats  (~33.7 MB)
    float* Vpart     = (float*)d_ws;
    float* asum_part = Vpart + (size_t)GRID * KK * DD;
    float* Vred      = asum_part + (size_t)GRID * KK;
    float* asum_red  = Vred + KK * DD;

    // no memset needed: all partials are fully overwritten with plain stores
    netvlad_fused<<<GRID, BLOCK, 0, stream>>>(x, conv_w, conv_b, Vpart, asum_part);
    netvlad_reduce<<<257, 256, 0, stream>>>(Vpart, asum_part, Vred, asum_red);
    netvlad_finalize<<<1, 1024, 0, stream>>>(Vred, asum_red, c, y);
}

// Round 7
// 101.423 us; speedup vs baseline: 3.0194x; 1.1145x over previous
//
#include <hip/hip_runtime.h>
#include <hip/hip_bf16.h>

// Problem constants
#define DD    256        // descriptor dim
#define KK    64         // clusters
#define NPIX  262144     // H*W
#define NW    512        // n-window (per window)
#define NWIN  2          // windows per block
#define GRID  256        // GRID * NWIN * NW == NPIX ; 1 block per CU
#define BLOCK 1024       // 16 waves, 1 block/CU (LDS-bound)

// LDS strides (elements)
#define W_S   264        // W:    [64][264] bf16 (row 528 B, 16B-mult)
#define AB_S  520        // abar: [64][520] bf16 (row 1040 B, 16B-mult)
#define XC_S  40         // phase-1 slice rows: 40 shorts = 80 B (16B-mult)
#define SV_S  129        // V stage: [64][129] f32 (half of d at a time)

typedef __attribute__((ext_vector_type(8))) short bf16x8;
typedef __attribute__((ext_vector_type(4))) float f32x4;

union Frag { bf16x8 v; int i[4]; };

__device__ __forceinline__ int cvtpk(float a, float b) {
    // packed f32->bf16 RNE; lowers to v_cvt_pk_bf16_f32 on gfx950
    __hip_bfloat162 h = __float22bfloat162_rn(float2{a, b});
    int r; __builtin_memcpy(&r, &h, 4); return r;  // low short = a
}

// lgkm-only barrier: LDS visibility without draining in-flight global loads
// (__syncthreads emits s_waitcnt vmcnt(0) which would kill cross-barrier prefetch)
__device__ __forceinline__ void lds_barrier() {
    asm volatile("s_waitcnt lgkmcnt(0)" ::: "memory");
    __builtin_amdgcn_s_barrier();
}

__global__ __launch_bounds__(BLOCK, 4)
void netvlad_fused(const float* __restrict__ x, const float* __restrict__ conv_w,
                   const float* __restrict__ conv_b, float* __restrict__ Vpart,
                   float* __restrict__ asum_part)
{
    __shared__ short Wl[KK * W_S];    // 33792 B
    __shared__ short Ab[KK * AB_S];   // 66560 B
    __shared__ union {
        short slice[16 * 32 * XC_S];  // 40960 B: 16 wave-private 32x40 xnd slices
        float sv[KK * SV_S];          // 33024 B: epilogue staging
    } U2;
    // total 141312 B -> 1 block/CU

    const int t    = threadIdx.x;
    const int lane = t & 63;
    const int w    = t >> 6;        // wave 0..15
    const int l15  = lane & 15;
    const int q    = (lane >> 4) & 3;
    const int bid  = blockIdx.x;
    const size_t n0 = (size_t)bid * (NWIN * NW);

    // ---- phase-1 load mapping: wave-private 32-col slice, chunks of 32 d ----
    const int dg = lane >> 3;            // 0..7  (4 d-rows each)
    const int ng = lane & 7;             // 0..7  (4 n-cols each)
    const size_t nself0 = n0 + 32 * w + 4 * ng;          // window 0
    const size_t nself1 = n0 + NW + 32 * w + 4 * ng;     // window 1

    // prologue: window-0 chunk 0 loads (overlap W staging)
    float4 pr[2][4];
    #pragma unroll
    for (int j = 0; j < 4; ++j)
        pr[0][j] = *(const float4*)(x + (size_t)(4 * dg + j) * NPIX + nself0);
    __builtin_amdgcn_sched_barrier(0);   // pin: do not sink these loads

    // ---- stage W (fp32 -> bf16) into LDS, ONCE per block ----
    #pragma unroll
    for (int i = 0; i < 16; ++i) {
        int idx = t + BLOCK * i;                 // 0..16383
        float wv = conv_w[idx];
        __hip_bfloat16 hb = __float2bfloat16(wv);
        short s; __builtin_memcpy(&s, &hb, 2);
        Wl[(idx >> 8) * W_S + (idx & 255)] = s;
    }

    // prologue: window-0 chunk 1 loads
    #pragma unroll
    for (int j = 0; j < 4; ++j)
        pr[1][j] = *(const float4*)(x + (size_t)(32 + 4 * dg + j) * NPIX + nself0);
    __builtin_amdgcn_sched_barrier(0);   // pin

    lds_barrier();   // W visible; pr loads stay in flight

    // cross-window accumulators
    float asumReg = 0.f;                 // valid for t < KK
    f32x4 acc[4];
    #pragma unroll
    for (int ct = 0; ct < 4; ++ct) acc[ct] = (f32x4){0.f, 0.f, 0.f, 0.f};

    short* slice = &U2.slice[w * (32 * XC_S)];

    #pragma unroll
    for (int win = 0; win < NWIN; ++win) {
        const size_t nwin   = n0 + (size_t)win * NW;
        const size_t nselfw = nwin + 32 * w + 4 * ng;

        // ============== PHASE 1: logits, wave-private, NO barriers ========
        f32x4 Lc[2][4];
        #pragma unroll
        for (int nt = 0; nt < 2; ++nt)
            #pragma unroll
            for (int mt = 0; mt < 4; ++mt)
                Lc[nt][mt] = (f32x4){0.f, 0.f, 0.f, 0.f};

        #pragma unroll
        for (int ch = 0; ch < 8; ++ch) {
            const int cur = ch & 1;

            // stage pr[cur] -> private slice (n-major micro-transpose), b64 writes
            {
                const float* r0 = (const float*)&pr[cur][0];
                const float* r1 = (const float*)&pr[cur][1];
                const float* r2 = (const float*)&pr[cur][2];
                const float* r3 = (const float*)&pr[cur][3];
                #pragma unroll
                for (int c = 0; c < 4; ++c) {
                    int2 pk; pk.x = cvtpk(r0[c], r1[c]); pk.y = cvtpk(r2[c], r3[c]);
                    *(int2*)&slice[(4 * ng + c) * XC_S + 4 * dg] = pk;
                }
            }

            // depth-2 prefetch: issue chunk ch+2 (regs just freed by staging)
            if (ch < 6) {
                #pragma unroll
                for (int j = 0; j < 4; ++j)
                    pr[cur][j] = *(const float4*)(x + (size_t)(32 * (ch + 2) + 4 * dg + j) * NPIX + nselfw);
                __builtin_amdgcn_sched_barrier(0);   // pin: keep prefetch issued HERE
            }

            // frags + MFMA (contraction over this 32-d chunk); A from LDS Wl
            Frag Bv[2];
            #pragma unroll
            for (int nt = 0; nt < 2; ++nt)
                Bv[nt] = *(const Frag*)&slice[(16 * nt + l15) * XC_S + 8 * q];
            #pragma unroll
            for (int mt = 0; mt < 4; ++mt) {
                Frag A = *(const Frag*)&Wl[(16 * mt + l15) * W_S + 32 * ch + 8 * q];
                #pragma unroll
                for (int nt = 0; nt < 2; ++nt)
                    Lc[nt][mt] = __builtin_amdgcn_mfma_f32_16x16x32_bf16(A.v, Bv[nt].v, Lc[nt][mt], 0, 0, 0);
            }
        }

        // ---- softmax over k (in-register, wave-local) ----
        float breg[4][4];
        #pragma unroll
        for (int mt = 0; mt < 4; ++mt)
            #pragma unroll
            for (int r = 0; r < 4; ++r)
                breg[mt][r] = conv_b[16 * mt + 4 * q + r];

        #pragma unroll
        for (int nt = 0; nt < 2; ++nt) {
            float mx = -1e30f;
            #pragma unroll
            for (int mt = 0; mt < 4; ++mt)
                #pragma unroll
                for (int r = 0; r < 4; ++r) {
                    Lc[nt][mt][r] += breg[mt][r];
                    mx = fmaxf(mx, Lc[nt][mt][r]);
                }
            mx = fmaxf(mx, __shfl_xor(mx, 16));
            mx = fmaxf(mx, __shfl_xor(mx, 32));
            float s = 0.f;
            #pragma unroll
            for (int mt = 0; mt < 4; ++mt)
                #pragma unroll
                for (int r = 0; r < 4; ++r) {
                    float e = __expf(Lc[nt][mt][r] - mx);
                    Lc[nt][mt][r] = e;
                    s += e;
                }
            s += __shfl_xor(s, 16);
            s += __shfl_xor(s, 32);
            float inv = 1.0f / s;
            #pragma unroll
            for (int mt = 0; mt < 4; ++mt)
                #pragma unroll
                for (int r = 0; r < 4; ++r)
                    Lc[nt][mt][r] *= inv;
        }

        // asum partials (this wave's 32 cols) -> wave-private LDS buf (dead slice area)
        {
            float* buf = (float*)(U2.slice + w * (32 * XC_S));   // 64 floats
            #pragma unroll
            for (int mt = 0; mt < 4; ++mt)
                #pragma unroll
                for (int r = 0; r < 4; ++r) {
                    float v = Lc[0][mt][r] + Lc[1][mt][r];
                    v += __shfl_xor(v, 1);
                    v += __shfl_xor(v, 2);
                    v += __shfl_xor(v, 4);
                    v += __shfl_xor(v, 8);
                    if (l15 == 0) buf[16 * mt + 4 * q + r] = v;
                }
        }

        // abar -> LDS (bf16), wave-private columns
        // (safe: win 0 gated by W-stage barrier; win 1 gated by end-of-p2 barrier)
        #pragma unroll
        for (int nt = 0; nt < 2; ++nt)
            #pragma unroll
            for (int mt = 0; mt < 4; ++mt)
                #pragma unroll
                for (int r = 0; r < 4; ++r) {
                    __hip_bfloat16 hb = __float2bfloat16(Lc[nt][mt][r]);
                    short s; __builtin_memcpy(&s, &hb, 2);
                    Ab[(16 * mt + 4 * q + r) * AB_S + 32 * w + 16 * nt + l15] = s;
                }

        // ---- phase-2 prologue: depth-4 pipeline issued BEFORE the barrier ----
        const float* xroww = x + (size_t)(16 * w + l15) * NPIX + nwin + 8 * q;
        float4 pv[4][2];
        #pragma unroll
        for (int d = 0; d < 4; ++d) {
            pv[d][0] = *(const float4*)(xroww + 32 * d);
            pv[d][1] = *(const float4*)(xroww + 32 * d + 4);
        }
        __builtin_amdgcn_sched_barrier(0);   // pin prologue issue

        // seam prefetch: issue NEXT window's phase-1 chunks 0,1 now (pr regs dead).
        // Issued AFTER pv so p2 step-0's vmcnt wait does not force these cold loads.
        if (win == 0) {
            #pragma unroll
            for (int j = 0; j < 4; ++j)
                pr[0][j] = *(const float4*)(x + (size_t)(4 * dg + j) * NPIX + nself1);
            #pragma unroll
            for (int j = 0; j < 4; ++j)
                pr[1][j] = *(const float4*)(x + (size_t)(32 + 4 * dg + j) * NPIX + nself1);
            __builtin_amdgcn_sched_barrier(0);   // pin
        }

        lds_barrier();   // ALL abar + asum bufs visible; pv/pr loads stay in flight

        // ---- block asum: 64 threads sum the 16 wave-bufs into registers ----
        if (t < KK) {
            float s = 0.f;
            #pragma unroll
            for (int ww = 0; ww < 16; ++ww)
                s += ((const float*)(U2.slice + ww * (32 * XC_S)))[t];
            asumReg += s;
        }

        // ========= PHASE 2: VLAD GEMM, direct-load A frags, NO barriers ====
        #pragma unroll
        for (int s = 0; s < 16; ++s) {
            const int cur = s & 3;
            Frag Af;
            Af.i[0] = cvtpk(pv[cur][0].x, pv[cur][0].y);
            Af.i[1] = cvtpk(pv[cur][0].z, pv[cur][0].w);
            Af.i[2] = cvtpk(pv[cur][1].x, pv[cur][1].y);
            Af.i[3] = cvtpk(pv[cur][1].z, pv[cur][1].w);
            if (s < 12) {   // depth-4 prefetch
                pv[cur][0] = *(const float4*)(xroww + 32 * (s + 4));
                pv[cur][1] = *(const float4*)(xroww + 32 * (s + 4) + 4);
                __builtin_amdgcn_sched_barrier(0);   // pin: keep prefetch issued HERE
            }
            Frag Bf[4];
            #pragma unroll
            for (int ct = 0; ct < 4; ++ct)
                Bf[ct] = *(const Frag*)&Ab[(16 * ct + l15) * AB_S + 32 * s + 8 * q];
            #pragma unroll
            for (int ct = 0; ct < 4; ++ct)
                acc[ct] = __builtin_amdgcn_mfma_f32_16x16x32_bf16(Af.v, Bf[ct].v, acc[ct], 0, 0, 0);
        }

        if (win == 0)
            lds_barrier();   // all waves done with Ab reads + slices -> window 1 may reuse
    }

    // ---- epilogue (once per block): V partial -> LDS halves -> plain stores ----
    // acc element (ct, r): k = 16ct + l15, d = 16w + 4q + r
    if (t < KK) asum_part[(size_t)bid * KK + t] = asumReg;

    float* vout = Vpart + (size_t)bid * (KK * DD);
    #pragma unroll
    for (int H = 0; H < 2; ++H) {
        __syncthreads();
        if ((w >> 3) == H) {
            #pragma unroll
            for (int ct = 0; ct < 4; ++ct)
                #pragma unroll
                for (int r = 0; r < 4; ++r) {
                    int k  = 16 * ct + l15;
                    int dl = 16 * w + 4 * q + r - 128 * H;
                    U2.sv[k * SV_S + dl] = acc[ct][r];
                }
        }
        __syncthreads();
        #pragma unroll
        for (int i = 0; i < 8; ++i) {
            int idx = t + BLOCK * i;       // 0..8191
            int k = idx >> 7, dl = idx & 127;
            vout[k * DD + 128 * H + dl] = U2.sv[k * SV_S + dl];
        }
    }
}

__global__ __launch_bounds__(256)
void netvlad_reduce(const float* __restrict__ Vpart, const float* __restrict__ asum_part,
                    float* __restrict__ Vred, float* __restrict__ asum_red)
{
    __shared__ float sbuf[256];
    const int t = threadIdx.x;
    if (blockIdx.x < 256) {
        // V: each block produces 64 outputs; 4 thread-groups of 64 split the 256 partials
        const int o = blockIdx.x * 64 + (t & 63);
        const int g = t >> 6;
        float s = 0.f;
        #pragma unroll 8
        for (int i = 0; i < 64; ++i)
            s += Vpart[(size_t)(g * 64 + i) * (KK * DD) + o];
        sbuf[t] = s;
        __syncthreads();
        if (t < 64) Vred[o] = sbuf[t] + sbuf[t + 64] + sbuf[t + 128] + sbuf[t + 192];
    } else {
        const int k = t & 63;
        const int g = t >> 6;
        float s = 0.f;
        #pragma unroll 8
        for (int i = 0; i < 64; ++i)
            s += asum_part[(size_t)(g * 64 + i) * KK + k];
        sbuf[t] = s;
        __syncthreads();
        if (t < 64) asum_red[k] = sbuf[t] + sbuf[t + 64] + sbuf[t + 128] + sbuf[t + 192];
    }
}

__global__ __launch_bounds__(1024)
void netvlad_finalize(const float* __restrict__ Vws, const float* __restrict__ asum_ws,
                      const float* __restrict__ c, float* __restrict__ y)
{
    __shared__ float sV[KK * DD];
    __shared__ float sa[KK];
    __shared__ float colf[DD];
    __shared__ float rowf[KK];
    const int t = threadIdx.x;

    if (t < KK) sa[t] = asum_ws[t];
    __syncthreads();

    #pragma unroll
    for (int i = 0; i < 16; ++i) {
        int idx = t + 1024 * i;
        sV[idx] = Vws[idx] - c[idx] * sa[idx >> 8];
    }
    __syncthreads();

    if (t < DD) {   // column (d) norms over k
        float s = 0.f;
        for (int k = 0; k < KK; ++k) { float v = sV[k * DD + t]; s += v * v; }
        colf[t] = 1.0f / fmaxf(sqrtf(s), 1e-12f);
    }
    __syncthreads();

    #pragma unroll
    for (int i = 0; i < 16; ++i) {
        int idx = t + 1024 * i;
        sV[idx] *= colf[idx & 255];
    }
    __syncthreads();

    {   // row (k) norms over d: 16 threads per row
        int k = t >> 4, p = t & 15;
        float s = 0.f;
        #pragma unroll
        for (int j = 0; j < 16; ++j) { float v = sV[k * DD + p + 16 * j]; s += v * v; }
        s += __shfl_xor(s, 1);
        s += __shfl_xor(s, 2);
        s += __shfl_xor(s, 4);
        s += __shfl_xor(s, 8);
        if (p == 0) rowf[k] = 1.0f / fmaxf(sqrtf(s), 1e-12f);
    }
    __syncthreads();

    #pragma unroll
    for (int i = 0; i < 16; ++i) {
        int idx = t + 1024 * i;
        y[idx] = sV[idx] * rowf[idx >> 8];
    }
}

extern "C" void kernel_launch(void* const* d_in, const int* in_sizes, int n_in,
                              void* d_out, int out_size, void* d_ws, size_t ws_size,
                              hipStream_t stream) {
    const float* x      = (const float*)d_in[0];
    const float* c      = (const float*)d_in[1];
    const float* conv_w = (const float*)d_in[2];
    const float* conv_b = (const float*)d_in[3];
    float* y = (float*)d_out;

    // workspace: 256*16384 + 256*64 + 16384 + 64 floats (~16.9 MB)
    float* Vpart     = (float*)d_ws;
    float* asum_part = Vpart + (size_t)GRID * KK * DD;
    float* Vred      = asum_part + (size_t)GRID * KK;
    float* asum_red  = Vred + KK * DD;

    // no memset needed: all partials are fully overwritten with plain stores
    netvlad_fused<<<GRID, BLOCK, 0, stream>>>(x, conv_w, conv_b, Vpart, asum_part);
    netvlad_reduce<<<257, 256, 0, stream>>>(Vpart, asum_part, Vred, asum_red);
    netvlad_finalize<<<1, 1024, 0, stream>>>(Vred, asum_red, c, y);
}